// Round 3
// baseline (1896.999 us; speedup 1.0000x reference)
//
#include <hip/hip_runtime.h>
#include <cstddef>

#define NS 26

typedef short bf16x8 __attribute__((ext_vector_type(8)));
typedef float f32x4 __attribute__((ext_vector_type(4)));

__device__ __forceinline__ float tanh_fast(float x) { return 1.f - 2.f / (__expf(2.f * x) + 1.f); }
__device__ __forceinline__ float sigf(float x) { return 1.f / (1.f + __expf(-x)); }
__device__ __forceinline__ unsigned short f2bf(float x) {
    unsigned int u = __float_as_uint(x);
    return (unsigned short)((u + 0x7FFFu + ((u >> 16) & 1u)) >> 16);
}

// ---------------- fp32 -> bf16 converts ----------------
__global__ __launch_bounds__(256) void conv_f32_bf16(const float* __restrict__ s,
                                                     unsigned short* __restrict__ d, int n4) {
    int i = blockIdx.x * 256 + threadIdx.x;
    if (i >= n4) return;
    float4 v = ((const float4*)s)[i];
    ushort4 o; o.x = f2bf(v.x); o.y = f2bf(v.y); o.z = f2bf(v.z); o.w = f2bf(v.w);
    ((ushort4*)d)[i] = o;
}
// W_ih[2048][608] -> first 512 cols as bf16 [2048][512]
__global__ __launch_bounds__(256) void conv_wih(const float* __restrict__ W,
                                                unsigned short* __restrict__ d) {
    int i = blockIdx.x * 256 + threadIdx.x;
    int row = i >> 7, c4 = (i & 127) << 2;
    float4 v = *(const float4*)(W + (size_t)row * 608 + c4);
    ushort4 o; o.x = f2bf(v.x); o.y = f2bf(v.y); o.z = f2bf(v.z); o.w = f2bf(v.w);
    *(ushort4*)(d + (size_t)row * 512 + c4) = o;
}
__global__ __launch_bounds__(256) void bias_sum(const float* __restrict__ a,
                                                const float* __restrict__ b,
                                                float* __restrict__ o) {
    int i = blockIdx.x * 256 + threadIdx.x;
    o[i] = a[i] + b[i];
}

// ---------------------------------------------------------------------------
// bf16 NT MFMA GEMM: C[M,N] = A[M,K](lda) * B[N,K](ldb)^T
// 64x64 tile, BK=64, 256 thr = 4 waves (2x2), wave 32x32 (2x2 frags).
// MODE 0: bf16 out. MODE 3: f32 out + bias, cols masked n<Nreal.
// MSWAP: 1 -> bm from blockIdx.x (XCD-locality for A-sharing n-blocks).
// ---------------------------------------------------------------------------
template <int MODE, int MSWAP>
__global__ __launch_bounds__(256) void gemm_bf16(
    const unsigned short* __restrict__ A, int lda,
    const unsigned short* __restrict__ B, int ldb,
    void* __restrict__ Cout, int ldc,
    const float* __restrict__ bias, int K, int Nreal)
{
    __shared__ unsigned short As[2][64][72];
    __shared__ unsigned short Bs[2][64][72];
    const int tid = threadIdx.x;
    const int bm = (MSWAP ? blockIdx.x : blockIdx.y) << 6;
    const int bn = (MSWAP ? blockIdx.y : blockIdx.x) << 6;
    const int w = tid >> 6, lane = tid & 63;
    const int wr = w >> 1, wc = w & 1;
    const int srow = tid >> 2, schunk = (tid & 3) << 4;
    int brow = bn + srow;
    if (MODE == 3) brow = min(brow, Nreal - 1);
    const unsigned short* Ap = A + (size_t)(bm + srow) * lda + schunk;
    const unsigned short* Bp = B + (size_t)brow * ldb + schunk;
    const int fr = lane & 15, fq = lane >> 4;

    uint4 ra0, ra1, rb0, rb1;
    f32x4 acc[2][2];
#pragma unroll
    for (int i = 0; i < 2; i++)
#pragma unroll
        for (int j = 0; j < 2; j++) acc[i][j] = f32x4{0.f, 0.f, 0.f, 0.f};

    const int NTk = K >> 6;
#define LOADR(t) { ra0 = *(const uint4*)(Ap + ((t) << 6)); ra1 = *(const uint4*)(Ap + ((t) << 6) + 8); \
                   rb0 = *(const uint4*)(Bp + ((t) << 6)); rb1 = *(const uint4*)(Bp + ((t) << 6) + 8); }
#define WRITEB(cb) { *(uint4*)&As[cb][srow][schunk] = ra0; *(uint4*)&As[cb][srow][schunk + 8] = ra1; \
                     *(uint4*)&Bs[cb][srow][schunk] = rb0; *(uint4*)&Bs[cb][srow][schunk + 8] = rb1; }
    LOADR(0); WRITEB(0);
    LOADR(1);
    __syncthreads();
    for (int t = 0; t < NTk; t++) {
        const int cb = t & 1;
        if (t + 1 < NTk) WRITEB(cb ^ 1);
        if (t + 2 < NTk) LOADR(t + 2);
        bf16x8 af[2][2], bfr[2][2];
#pragma unroll
        for (int fi = 0; fi < 2; fi++)
#pragma unroll
            for (int ks = 0; ks < 2; ks++) {
                af[fi][ks]  = *(const bf16x8*)&As[cb][(wr << 5) + (fi << 4) + fr][(ks << 5) + (fq << 3)];
                bfr[fi][ks] = *(const bf16x8*)&Bs[cb][(wc << 5) + (fi << 4) + fr][(ks << 5) + (fq << 3)];
            }
#pragma unroll
        for (int fi = 0; fi < 2; fi++)
#pragma unroll
            for (int fj = 0; fj < 2; fj++)
#pragma unroll
                for (int ks = 0; ks < 2; ks++)
                    acc[fi][fj] = __builtin_amdgcn_mfma_f32_16x16x32_bf16(
                        af[fi][ks], bfr[fj][ks], acc[fi][fj], 0, 0, 0);
        __syncthreads();
    }
#undef LOADR
#undef WRITEB
#pragma unroll
    for (int fi = 0; fi < 2; fi++) {
        const int mbase = bm + (wr << 5) + (fi << 4) + (fq << 2);
#pragma unroll
        for (int fj = 0; fj < 2; fj++) {
            const int n = bn + (wc << 5) + (fj << 4) + fr;
            f32x4 v = acc[fi][fj];
            if (MODE == 0) {
                unsigned short* C = (unsigned short*)Cout;
#pragma unroll
                for (int r = 0; r < 4; r++) C[(size_t)(mbase + r) * ldc + n] = f2bf(v[r]);
            } else {
                if (n < Nreal) {
                    float* C = (float*)Cout;
                    const float bb = bias[n];
#pragma unroll
                    for (int r = 0; r < 4; r++) C[(size_t)(mbase + r) * ldc + n] = v[r] + bb;
                }
            }
        }
    }
}

// ---------------------------------------------------------------------------
// Fused gates GEMM + LSTM pointwise + next-step ph partial.
// Grid (8 nblk x, 16 mblk y), 256 thr. m-tile 32, n-tile 64 (h-cols).
// Phase1: gates[m,4*512] slice via MFMA, wave g owns gate g (32x64).
// Phase2: LDS exchange -> pointwise LSTM -> c, hs, hnew, h_tile.
// Phase3: ph_part[nblk][m][512] = h_tile @ W_h2h[:, n0:n0+64]^T.
// ---------------------------------------------------------------------------
__global__ __launch_bounds__(256) void gates_lstm_ph(
    const unsigned short* __restrict__ ctx,     // [512][512] bf16
    const unsigned short* __restrict__ hprev,   // [512][512] bf16
    const unsigned short* __restrict__ Wihcb,   // [2048][512] bf16
    const unsigned short* __restrict__ Whhb,    // [2048][512] bf16
    const float* __restrict__ W_ih_f32,         // [2048][608]
    const float* __restrict__ bsum,             // [2048] = b_ih + b_hh
    const int* __restrict__ text, int sstep,
    float* __restrict__ c,                      // [512][512]
    unsigned short* __restrict__ hs,            // [512][26][512] bf16
    unsigned short* __restrict__ hnew,          // [512][512] bf16
    float* __restrict__ ph_part,                // [8][512][512]
    const unsigned short* __restrict__ Wh2hb)   // [512][512] bf16
{
    __shared__ __align__(16) char smem[78336];
    unsigned short (*As)[72]  = (unsigned short(*)[72])smem;           // [32][72]
    unsigned short (*Bs)[72]  = (unsigned short(*)[72])(smem + 4608);  // [256][72]
    float (*gf)[32][68]       = (float(*)[32][68])(smem + 4608);       // [4][32][68]
    unsigned short (*ht)[72]  = (unsigned short(*)[72])smem;           // [32][72]
    unsigned short (*Wsl)[72] = (unsigned short(*)[72])(smem + 4608);  // [512][72]

    const int tid = threadIdx.x;
    const int w = tid >> 6, lane = tid & 63;
    const int fr = lane & 15, fq = lane >> 4;
    const int nblk = blockIdx.x, n0 = nblk << 6, m0 = blockIdx.y << 5;
    const int arow = tid >> 3, acol = (tid & 7) << 3;   // arow 0..31

    // ---- Phase 1: gates GEMM, K=1024 (ctx | hprev), 16 K-tiles of 64 ----
    uint4 ra, rb[8];
#define GLOAD(kt) { const int k0 = (kt) << 6; \
    const unsigned short* Ab = (k0 < 512) ? ctx : hprev; \
    const unsigned short* Wb = (k0 < 512) ? Wihcb : Whhb; \
    const int kk = k0 & 511; \
    ra = *(const uint4*)(Ab + (size_t)(m0 + arow) * 512 + kk + acol); \
    _Pragma("unroll") for (int j = 0; j < 8; j++) { \
        const int br = arow + (j << 5); \
        const int ng = ((br >> 6) << 9) + n0 + (br & 63); \
        rb[j] = *(const uint4*)(Wb + (size_t)ng * 512 + kk + acol); } }

    f32x4 acc[2][4];
#pragma unroll
    for (int i = 0; i < 2; i++)
#pragma unroll
        for (int j = 0; j < 4; j++) acc[i][j] = f32x4{0.f, 0.f, 0.f, 0.f};

    GLOAD(0);
    for (int kt = 0; kt < 16; kt++) {
        __syncthreads();
        *(uint4*)&As[arow][acol] = ra;
#pragma unroll
        for (int j = 0; j < 8; j++) *(uint4*)&Bs[arow + (j << 5)][acol] = rb[j];
        __syncthreads();
        if (kt < 15) GLOAD(kt + 1);
        bf16x8 af[2][2], bf[4][2];
#pragma unroll
        for (int fi = 0; fi < 2; fi++)
#pragma unroll
            for (int ks = 0; ks < 2; ks++)
                af[fi][ks] = *(const bf16x8*)&As[(fi << 4) + fr][(ks << 5) + (fq << 3)];
#pragma unroll
        for (int fj = 0; fj < 4; fj++)
#pragma unroll
            for (int ks = 0; ks < 2; ks++)
                bf[fj][ks] = *(const bf16x8*)&Bs[(w << 6) + (fj << 4) + fr][(ks << 5) + (fq << 3)];
#pragma unroll
        for (int fi = 0; fi < 2; fi++)
#pragma unroll
            for (int fj = 0; fj < 4; fj++)
#pragma unroll
                for (int ks = 0; ks < 2; ks++)
                    acc[fi][fj] = __builtin_amdgcn_mfma_f32_16x16x32_bf16(
                        af[fi][ks], bf[fj][ks], acc[fi][fj], 0, 0, 0);
    }
#undef GLOAD
    __syncthreads();   // staging LDS dead; about to overwrite with gf

    // ---- Phase 2: gate exchange + LSTM pointwise ----
#pragma unroll
    for (int fi = 0; fi < 2; fi++)
#pragma unroll
        for (int fj = 0; fj < 4; fj++)
#pragma unroll
            for (int r = 0; r < 4; r++)
                gf[w][(fi << 4) + (fq << 2) + r][(fj << 4) + fr] = acc[fi][fj][r];
    __syncthreads();
#pragma unroll
    for (int p8 = 0; p8 < 8; p8++) {
        const int idx = (p8 << 8) + tid;
        const int m = idx >> 6, hcol = idx & 63;
        const int mg = m0 + m;
        const int tok = text[mg * NS + sstep];
        const int n1 = n0 + hcol;
        const float* wtok = W_ih_f32 + 512 + tok;
        const float gi = gf[0][m][hcol] + bsum[n1]        + wtok[(size_t)n1 * 608];
        const float gfv = gf[1][m][hcol] + bsum[512 + n1]  + wtok[(size_t)(512 + n1) * 608];
        const float gg = gf[2][m][hcol] + bsum[1024 + n1] + wtok[(size_t)(1024 + n1) * 608];
        const float go = gf[3][m][hcol] + bsum[1536 + n1] + wtok[(size_t)(1536 + n1) * 608];
        const float i_ = sigf(gi), f_ = sigf(gfv), g_ = tanh_fast(gg), o_ = sigf(go);
        const size_t ci = (size_t)mg * 512 + n1;
        const float cn = fmaf(f_, c[ci], i_ * g_);
        c[ci] = cn;
        const unsigned short hb = f2bf(o_ * tanh_fast(cn));
        hs[((size_t)mg * NS + sstep) * 512 + n1] = hb;
        hnew[ci] = hb;
        ht[m][hcol] = hb;
    }
    __syncthreads();   // gf reads done; ht visible; Wsl may now overwrite gf

    // ---- Phase 3: ph partial = ht[32,64] @ W_h2h[:, n0:n0+64]^T -> [32,512] ----
#pragma unroll
    for (int j = 0; j < 16; j++) {
        const int row = (tid >> 3) + (j << 5);
        *(uint4*)&Wsl[row][acol] = *(const uint4*)(Wh2hb + (size_t)row * 512 + n0 + acol);
    }
    __syncthreads();
    f32x4 acc2[2][8];
#pragma unroll
    for (int i = 0; i < 2; i++)
#pragma unroll
        for (int j = 0; j < 8; j++) acc2[i][j] = f32x4{0.f, 0.f, 0.f, 0.f};
    bf16x8 af2[2][2];
#pragma unroll
    for (int fi = 0; fi < 2; fi++)
#pragma unroll
        for (int ks = 0; ks < 2; ks++)
            af2[fi][ks] = *(const bf16x8*)&ht[(fi << 4) + fr][(ks << 5) + (fq << 3)];
#pragma unroll
    for (int fj = 0; fj < 8; fj++)
#pragma unroll
        for (int ks = 0; ks < 2; ks++) {
            const bf16x8 bv = *(const bf16x8*)&Wsl[(w << 7) + (fj << 4) + fr][(ks << 5) + (fq << 3)];
#pragma unroll
            for (int fi = 0; fi < 2; fi++)
                acc2[fi][fj] = __builtin_amdgcn_mfma_f32_16x16x32_bf16(
                    af2[fi][ks], bv, acc2[fi][fj], 0, 0, 0);
        }
#pragma unroll
    for (int fi = 0; fi < 2; fi++)
#pragma unroll
        for (int fj = 0; fj < 8; fj++) {
            const int p = (w << 7) + (fj << 4) + fr;
#pragma unroll
            for (int r = 0; r < 4; r++) {
                const int m = m0 + (fi << 4) + (fq << 2) + r;
                ph_part[((size_t)nblk * 512 + m) * 512 + p] = acc2[fi][fj][r];
            }
        }
}

// ---------------------------------------------------------------------------
// Attention: ph = b_h2h + sum_k ph_part[k][b][:]; scores; softmax; context.
// ---------------------------------------------------------------------------
__global__ __launch_bounds__(256) void attn_kernel(
    const unsigned short* __restrict__ H_proj,   // [B*64][512] bf16
    const float* __restrict__ ph_part,           // [8][512][512]
    const float* __restrict__ b_h2h,             // [512]
    const float* __restrict__ w_score,           // [512]
    const unsigned short* __restrict__ batch_H,  // [B*64][512] bf16
    unsigned short* __restrict__ ctx)            // [B][512] bf16
{
    __shared__ float s_ph[512];
    __shared__ float s_w[512];
    __shared__ float s_e[64];
    __shared__ float s_al[64];
    const int b = blockIdx.x;
    const int tid = threadIdx.x;
#pragma unroll
    for (int half = 0; half < 2; half++) {
        const int pp = tid + (half << 8);
        float v = b_h2h[pp];
#pragma unroll
        for (int k = 0; k < 8; k++) v += ph_part[(((size_t)k << 9) + b) * 512 + pp];
        s_ph[pp] = v;
        s_w[pp] = w_score[pp];
    }
    __syncthreads();

    const int w = tid >> 6, lane = tid & 63;
    for (int t = w; t < 64; t += 4) {
        const uint4 hv = *(const uint4*)(H_proj + ((size_t)b * 64 + t) * 512 + lane * 8);
        const int h0 = lane * 8;
        unsigned int ua[4] = {hv.x, hv.y, hv.z, hv.w};
        float acc = 0.f;
#pragma unroll
        for (int j = 0; j < 4; j++) {
            const float e0 = __uint_as_float(ua[j] << 16);
            const float e1 = __uint_as_float(ua[j] & 0xffff0000u);
            acc += tanh_fast(e0 + s_ph[h0 + 2 * j]) * s_w[h0 + 2 * j];
            acc += tanh_fast(e1 + s_ph[h0 + 2 * j + 1]) * s_w[h0 + 2 * j + 1];
        }
#pragma unroll
        for (int off = 32; off; off >>= 1) acc += __shfl_xor(acc, off);
        if (lane == 0) s_e[t] = acc;
    }
    __syncthreads();
    if (tid < 64) {
        float m = -1e30f;
        for (int t = 0; t < 64; ++t) m = fmaxf(m, s_e[t]);
        float sum = 0.f;
        for (int t = 0; t < 64; ++t) sum += __expf(s_e[t] - m);
        s_al[tid] = __expf(s_e[tid] - m) / sum;
    }
    __syncthreads();
    const unsigned int* bH = (const unsigned int*)(batch_H + (size_t)b * 64 * 512);
    float a0 = 0.f, a1 = 0.f;
    for (int t = 0; t < 64; ++t) {
        const unsigned int u = bH[t * 256 + tid];
        const float al = s_al[t];
        a0 = fmaf(al, __uint_as_float(u << 16), a0);
        a1 = fmaf(al, __uint_as_float(u & 0xffff0000u), a1);
    }
    const unsigned int o = ((unsigned int)f2bf(a1) << 16) | (unsigned int)f2bf(a0);
    ((unsigned int*)(ctx + (size_t)b * 512))[tid] = o;
}

// ---------------------------------------------------------------------------
extern "C" void kernel_launch(void* const* d_in, const int* in_sizes, int n_in,
                              void* d_out, int out_size, void* d_ws, size_t ws_size,
                              hipStream_t stream) {
    const float* batch_H = (const float*)d_in[0];   // [512,64,512]
    const int*   text    = (const int*)d_in[1];     // [512,26]
    const float* W_i2h   = (const float*)d_in[2];   // [512,512]
    const float* W_h2h   = (const float*)d_in[3];   // [512,512]
    const float* b_h2h   = (const float*)d_in[4];   // [512]
    const float* w_score = (const float*)d_in[5];   // [1,512]
    const float* W_ih    = (const float*)d_in[6];   // [2048,608]
    const float* b_ih    = (const float*)d_in[7];   // [2048]
    const float* W_hh    = (const float*)d_in[8];   // [2048,512]
    const float* b_hh    = (const float*)d_in[9];   // [2048]
    const float* W_gen   = (const float*)d_in[10];  // [96,512]
    const float* b_gen   = (const float*)d_in[11];  // [96]
    float* out = (float*)d_out;                     // [512,26,96]

    char* wsp = (char*)d_ws;
    auto alloc = [&](size_t bytes) { char* p = wsp; wsp += (bytes + 255) & ~(size_t)255; return p; };
    unsigned short* bH    = (unsigned short*)alloc(32768ull * 512 * 2);
    unsigned short* Hproj = (unsigned short*)alloc(32768ull * 512 * 2);
    unsigned short* hs    = (unsigned short*)alloc(512ull * NS * 512 * 2);
    unsigned short* hbuf0 = (unsigned short*)alloc(512ull * 512 * 2);
    unsigned short* hbuf1 = (unsigned short*)alloc(512ull * 512 * 2);
    unsigned short* ctx   = (unsigned short*)alloc(512ull * 512 * 2);
    unsigned short* Wi2hb = (unsigned short*)alloc(512ull * 512 * 2);
    unsigned short* Wh2hb = (unsigned short*)alloc(512ull * 512 * 2);
    unsigned short* Wihcb = (unsigned short*)alloc(2048ull * 512 * 2);
    unsigned short* Whhb  = (unsigned short*)alloc(2048ull * 512 * 2);
    unsigned short* Wgenb = (unsigned short*)alloc(96ull * 512 * 2);
    float* ph_part = (float*)alloc(8ull * 512 * 512 * 4);
    float* cst     = (float*)alloc(512ull * 512 * 4);
    float* bsum    = (float*)alloc(2048ull * 4);
    unsigned short* hb[2] = {hbuf0, hbuf1};

    hipMemsetAsync(hbuf1, 0, 512ull * 512 * 2, stream);
    hipMemsetAsync(cst, 0, 512ull * 512 * 4, stream);
    hipMemsetAsync(ph_part, 0, 8ull * 512 * 512 * 4, stream);

    conv_f32_bf16<<<16384, 256, 0, stream>>>(batch_H, bH, 4194304);
    conv_f32_bf16<<<256, 256, 0, stream>>>(W_i2h, Wi2hb, 65536);
    conv_f32_bf16<<<256, 256, 0, stream>>>(W_h2h, Wh2hb, 65536);
    conv_f32_bf16<<<1024, 256, 0, stream>>>(W_hh, Whhb, 262144);
    conv_f32_bf16<<<48, 256, 0, stream>>>(W_gen, Wgenb, 12288);
    conv_wih<<<1024, 256, 0, stream>>>(W_ih, Wihcb);
    bias_sum<<<8, 256, 0, stream>>>(b_ih, b_hh, bsum);

    // H_proj = batch_H @ W_i2h^T -> bf16 [32768,512]; x=m so A-sharers share an XCD
    gemm_bf16<0, 1><<<dim3(512, 8), 256, 0, stream>>>(bH, 512, Wi2hb, 512, Hproj, 512, nullptr, 512, 0);

    for (int s = 0; s < NS; ++s) {
        attn_kernel<<<512, 256, 0, stream>>>(Hproj, ph_part, b_h2h, w_score, bH, ctx);
        gates_lstm_ph<<<dim3(8, 16), 256, 0, stream>>>(
            ctx, hb[(s + 1) & 1], Wihcb, Whhb, W_ih, bsum, text, s,
            cst, hs, hb[s & 1], ph_part, Wh2hb);
    }

    // out = hs @ W_gen^T + b_gen (f32, N=96 masked in 128-wide tiles)
    gemm_bf16<3, 0><<<dim3(2, 208), 256, 0, stream>>>(hs, 512, Wgenb, 512, out, 96, b_gen, 512, 96);
}

// Round 4
// 1029.126 us; speedup vs baseline: 1.8433x; 1.8433x over previous
//
#include <hip/hip_runtime.h>
#include <cstddef>

#define NS 26

typedef short bf16x8 __attribute__((ext_vector_type(8)));
typedef float f32x4 __attribute__((ext_vector_type(4)));

__device__ __forceinline__ float tanh_fast(float x) { return 1.f - 2.f / (__expf(2.f * x) + 1.f); }
__device__ __forceinline__ float sigf(float x) { return 1.f / (1.f + __expf(-x)); }
__device__ __forceinline__ unsigned short f2bf(float x) {
    unsigned int u = __float_as_uint(x);
    return (unsigned short)((u + 0x7FFFu + ((u >> 16) & 1u)) >> 16);
}

// ---------------- setup converts ----------------
__global__ __launch_bounds__(256) void conv_f32_bf16(const float* __restrict__ s,
                                                     unsigned short* __restrict__ d, int n4) {
    int i = blockIdx.x * 256 + threadIdx.x;
    if (i >= n4) return;
    float4 v = ((const float4*)s)[i];
    ushort4 o; o.x = f2bf(v.x); o.y = f2bf(v.y); o.z = f2bf(v.z); o.w = f2bf(v.w);
    ((ushort4*)d)[i] = o;
}
// Gate-permuted weight: dst[n'][k], n' = h*4+g, src row n = g*512+h, cols [0,512) of stride
__global__ __launch_bounds__(256) void conv_w_perm(const float* __restrict__ src, int stride,
                                                   unsigned short* __restrict__ dst) {
    int i = blockIdx.x * 256 + threadIdx.x;       // over 2048 * 64 chunks of 8
    int np = i >> 6, k8 = (i & 63) << 3;
    int h = np >> 2, g = np & 3;
    const float* p = src + (size_t)(g * 512 + h) * stride + k8;
    float4 v0 = *(const float4*)p, v1 = *(const float4*)(p + 4);
    ushort4 o0, o1;
    o0.x = f2bf(v0.x); o0.y = f2bf(v0.y); o0.z = f2bf(v0.z); o0.w = f2bf(v0.w);
    o1.x = f2bf(v1.x); o1.y = f2bf(v1.y); o1.z = f2bf(v1.z); o1.w = f2bf(v1.w);
    *(ushort4*)(dst + (size_t)np * 512 + k8) = o0;
    *(ushort4*)(dst + (size_t)np * 512 + k8 + 4) = o1;
}
// Wtok_p[t][n'] = W_ih[g*512+h][512+t]  (f32, transposed+permuted one-hot table)
__global__ __launch_bounds__(256) void conv_wtok(const float* __restrict__ W_ih,
                                                 float* __restrict__ wtp) {
    int i = blockIdx.x * 256 + threadIdx.x;       // over 96*2048
    if (i >= 96 * 2048) return;
    int t = i >> 11, np = i & 2047;
    int h = np >> 2, g = np & 3;
    wtp[i] = W_ih[(size_t)(g * 512 + h) * 608 + 512 + t];
}
// bsum_p[n'] = b_ih[n] + b_hh[n]
__global__ __launch_bounds__(256) void bias_perm(const float* __restrict__ bi,
                                                 const float* __restrict__ bh,
                                                 float* __restrict__ o) {
    int i = blockIdx.x * 256 + threadIdx.x;
    int h = i >> 2, g = i & 3, n = g * 512 + h;
    o[i] = bi[n] + bh[n];
}

// ---------------------------------------------------------------------------
// bf16 NT MFMA GEMM: C[M,N] = A[M,K](lda)*B[N,K](ldb)^T. 64x64 tile, BK=64,
// 4 waves. MODE 0: bf16 out. MODE 3: f32 out + bias, cols masked n<Nreal.
// SWZ 1: H_proj XCD remap (grid must be dim3(512,8)).
// ---------------------------------------------------------------------------
template <int MODE, int SWZ>
__global__ __launch_bounds__(256) void gemm_bf16(
    const unsigned short* __restrict__ A, int lda,
    const unsigned short* __restrict__ B, int ldb,
    void* __restrict__ Cout, int ldc,
    const float* __restrict__ bias, int K, int Nreal)
{
    __shared__ unsigned short As[2][64][72];
    __shared__ unsigned short Bs[2][64][72];
    const int tid = threadIdx.x;
    int bm, bn;
    if (SWZ == 1) {
        const int l = blockIdx.x + (blockIdx.y << 9);
        const int cc = l & 7, k = l >> 3;            // k in 0..511
        bm = ((cc << 6) + (k >> 3)) << 6;            // 64 m-tiles per XCD chunk
        bn = (k & 7) << 6;
    } else {
        bm = blockIdx.y << 6;
        bn = blockIdx.x << 6;
    }
    const int w = tid >> 6, lane = tid & 63;
    const int wr = w >> 1, wc = w & 1;
    const int srow = tid >> 2, schunk = (tid & 3) << 4;
    int brow = bn + srow;
    if (MODE == 3) brow = min(brow, Nreal - 1);
    const unsigned short* Ap = A + (size_t)(bm + srow) * lda + schunk;
    const unsigned short* Bp = B + (size_t)brow * ldb + schunk;
    const int fr = lane & 15, fq = lane >> 4;

    uint4 ra0, ra1, rb0, rb1;
    f32x4 acc[2][2];
#pragma unroll
    for (int i = 0; i < 2; i++)
#pragma unroll
        for (int j = 0; j < 2; j++) acc[i][j] = f32x4{0.f, 0.f, 0.f, 0.f};

    const int NTk = K >> 6;
#define LOADR(t) { ra0 = *(const uint4*)(Ap + ((t) << 6)); ra1 = *(const uint4*)(Ap + ((t) << 6) + 8); \
                   rb0 = *(const uint4*)(Bp + ((t) << 6)); rb1 = *(const uint4*)(Bp + ((t) << 6) + 8); }
#define WRITEB(cb) { *(uint4*)&As[cb][srow][schunk] = ra0; *(uint4*)&As[cb][srow][schunk + 8] = ra1; \
                     *(uint4*)&Bs[cb][srow][schunk] = rb0; *(uint4*)&Bs[cb][srow][schunk + 8] = rb1; }
    LOADR(0); WRITEB(0);
    LOADR(1);
    __syncthreads();
    for (int t = 0; t < NTk; t++) {
        const int cb = t & 1;
        if (t + 1 < NTk) WRITEB(cb ^ 1);
        if (t + 2 < NTk) LOADR(t + 2);
        bf16x8 af[2][2], bfr[2][2];
#pragma unroll
        for (int fi = 0; fi < 2; fi++)
#pragma unroll
            for (int ks = 0; ks < 2; ks++) {
                af[fi][ks]  = *(const bf16x8*)&As[cb][(wr << 5) + (fi << 4) + fr][(ks << 5) + (fq << 3)];
                bfr[fi][ks] = *(const bf16x8*)&Bs[cb][(wc << 5) + (fi << 4) + fr][(ks << 5) + (fq << 3)];
            }
#pragma unroll
        for (int fi = 0; fi < 2; fi++)
#pragma unroll
            for (int fj = 0; fj < 2; fj++)
#pragma unroll
                for (int ks = 0; ks < 2; ks++)
                    acc[fi][fj] = __builtin_amdgcn_mfma_f32_16x16x32_bf16(
                        af[fi][ks], bfr[fj][ks], acc[fi][fj], 0, 0, 0);
        __syncthreads();
    }
#undef LOADR
#undef WRITEB
#pragma unroll
    for (int fi = 0; fi < 2; fi++) {
        const int mbase = bm + (wr << 5) + (fi << 4) + (fq << 2);
#pragma unroll
        for (int fj = 0; fj < 2; fj++) {
            const int n = bn + (wc << 5) + (fj << 4) + fr;
            f32x4 v = acc[fi][fj];
            if (MODE == 0) {
                unsigned short* C = (unsigned short*)Cout;
#pragma unroll
                for (int r = 0; r < 4; r++) C[(size_t)(mbase + r) * ldc + n] = f2bf(v[r]);
            } else {
                if (n < Nreal) {
                    float* C = (float*)Cout;
                    const float bb = bias[n];
#pragma unroll
                    for (int r = 0; r < 4; r++) C[(size_t)(mbase + r) * ldc + n] = v[r] + bb;
                }
            }
        }
    }
}

// ---------------------------------------------------------------------------
// Fused gates GEMM (gate-permuted N) + LSTM pointwise.
// Grid (32,8) XCD-swizzled -> 256 blocks, 64m x 64n' tile, K=1024 (ctx|hprev).
// n' = h*4+g: block tile = all 4 gates for 16 h-cols -> pointwise in-block.
// ---------------------------------------------------------------------------
__global__ __launch_bounds__(256) void gates_lstm(
    const unsigned short* __restrict__ ctx,     // [512][512] bf16
    const unsigned short* __restrict__ hprev,   // [512][512] bf16
    const unsigned short* __restrict__ Wgi,     // [2048][512] bf16 perm (W_ih[:, :512])
    const unsigned short* __restrict__ Wgh,     // [2048][512] bf16 perm (W_hh)
    const float* __restrict__ bsum_p,           // [2048] perm
    const float* __restrict__ Wtok_p,           // [96][2048] perm f32
    const int* __restrict__ text, int sstep,
    float* __restrict__ c,                      // [512][512] f32
    unsigned short* __restrict__ hs,            // [512][26][512] bf16
    unsigned short* __restrict__ hnew)          // [512][512] bf16
{
    __shared__ __align__(16) char smem[36864];
    unsigned short (*As)[64][72] = (unsigned short(*)[64][72])smem;
    unsigned short (*Bs)[64][72] = (unsigned short(*)[64][72])(smem + 18432);
    float (*gls)[68] = (float(*)[68])smem;   // [64][68] alias, 17.4KB

    const int tid = threadIdx.x;
    const int l = blockIdx.x + (blockIdx.y << 5);
    const int cc = l & 7, kq = l >> 3;              // kq 0..31
    const int nblk = (cc << 2) + (kq >> 3);         // 4 n'-panels per XCD
    const int m0 = (kq & 7) << 6;
    const int bn_ = nblk << 6;
    const int w = tid >> 6, lane = tid & 63;
    const int wr = w >> 1, wc = w & 1;
    const int srow = tid >> 2, schunk = (tid & 3) << 4;
    const int fr = lane & 15, fq = lane >> 4;

    const unsigned short* Ac = ctx   + (size_t)(m0 + srow) * 512 + schunk;
    const unsigned short* Ah = hprev + (size_t)(m0 + srow) * 512 + schunk;
    const unsigned short* Bi = Wgi + (size_t)(bn_ + srow) * 512 + schunk;
    const unsigned short* Bh = Wgh + (size_t)(bn_ + srow) * 512 + schunk;

    uint4 ra0, ra1, rb0, rb1;
    f32x4 acc[2][2];
#pragma unroll
    for (int i = 0; i < 2; i++)
#pragma unroll
        for (int j = 0; j < 2; j++) acc[i][j] = f32x4{0.f, 0.f, 0.f, 0.f};

#define GLOAD(t) { const int tt = (t); \
    const unsigned short* ap = (tt < 8) ? Ac + (tt << 6) : Ah + ((tt - 8) << 6); \
    const unsigned short* bp = (tt < 8) ? Bi + (tt << 6) : Bh + ((tt - 8) << 6); \
    ra0 = *(const uint4*)ap; ra1 = *(const uint4*)(ap + 8); \
    rb0 = *(const uint4*)bp; rb1 = *(const uint4*)(bp + 8); }
#define WRITEB(cb) { *(uint4*)&As[cb][srow][schunk] = ra0; *(uint4*)&As[cb][srow][schunk + 8] = ra1; \
                     *(uint4*)&Bs[cb][srow][schunk] = rb0; *(uint4*)&Bs[cb][srow][schunk + 8] = rb1; }
    GLOAD(0); WRITEB(0);
    GLOAD(1);
    __syncthreads();
    for (int t = 0; t < 16; t++) {
        const int cb = t & 1;
        if (t + 1 < 16) WRITEB(cb ^ 1);
        if (t + 2 < 16) GLOAD(t + 2);
        bf16x8 af[2][2], bfr[2][2];
#pragma unroll
        for (int fi = 0; fi < 2; fi++)
#pragma unroll
            for (int ks = 0; ks < 2; ks++) {
                af[fi][ks]  = *(const bf16x8*)&As[cb][(wr << 5) + (fi << 4) + fr][(ks << 5) + (fq << 3)];
                bfr[fi][ks] = *(const bf16x8*)&Bs[cb][(wc << 5) + (fi << 4) + fr][(ks << 5) + (fq << 3)];
            }
#pragma unroll
        for (int fi = 0; fi < 2; fi++)
#pragma unroll
            for (int fj = 0; fj < 2; fj++)
#pragma unroll
                for (int ks = 0; ks < 2; ks++)
                    acc[fi][fj] = __builtin_amdgcn_mfma_f32_16x16x32_bf16(
                        af[fi][ks], bfr[fj][ks], acc[fi][fj], 0, 0, 0);
        __syncthreads();
    }
#undef GLOAD
#undef WRITEB

    // exchange: acc -> gls[64][68]
#pragma unroll
    for (int fi = 0; fi < 2; fi++)
#pragma unroll
        for (int fj = 0; fj < 2; fj++)
#pragma unroll
            for (int r = 0; r < 4; r++)
                gls[(wr << 5) + (fi << 4) + (fq << 2) + r][(wc << 5) + (fj << 4) + fr] = acc[fi][fj][r];
    __syncthreads();

    // pointwise: 1024 cells (64 m x 16 h), 4 per thread
    const int hbase = nblk << 4;
#pragma unroll
    for (int p = 0; p < 4; p++) {
        const int idx = (p << 8) + tid;
        const int ml = idx >> 4, hl = idx & 15;
        const int mg = m0 + ml, hg = hbase + hl;
        const int tok = text[mg * NS + sstep];
        const float4 gq = *(const float4*)&gls[ml][hl << 2];
        const float4 bq = *(const float4*)&bsum_p[bn_ + (hl << 2)];
        const float4 wq = *(const float4*)&Wtok_p[(size_t)tok * 2048 + bn_ + (hl << 2)];
        const float i_ = sigf(gq.x + bq.x + wq.x);
        const float f_ = sigf(gq.y + bq.y + wq.y);
        const float g_ = tanh_fast(gq.z + bq.z + wq.z);
        const float o_ = sigf(gq.w + bq.w + wq.w);
        const size_t ci = (size_t)mg * 512 + hg;
        const float cn = fmaf(f_, c[ci], i_ * g_);
        c[ci] = cn;
        const unsigned short hb = f2bf(o_ * tanh_fast(cn));
        hs[((size_t)mg * NS + sstep) * 512 + hg] = hb;
        hnew[ci] = hb;
    }
}

// ---------------------------------------------------------------------------
// Attention: scores -> softmax over t=64 -> context (bf16)
// ---------------------------------------------------------------------------
__global__ __launch_bounds__(256) void attn_kernel(
    const unsigned short* __restrict__ H_proj,   // [B*64][512] bf16
    const float* __restrict__ ph,                // [B][512] f32
    const float* __restrict__ w_score,           // [512]
    const unsigned short* __restrict__ batch_H,  // [B*64][512] bf16
    unsigned short* __restrict__ ctx)            // [B][512] bf16
{
    __shared__ float s_ph[512];
    __shared__ float s_w[512];
    __shared__ float s_e[64];
    __shared__ float s_al[64];
    const int b = blockIdx.x;
    const int tid = threadIdx.x;
    s_ph[tid] = ph[b * 512 + tid];
    s_ph[tid + 256] = ph[b * 512 + 256 + tid];
    s_w[tid] = w_score[tid];
    s_w[tid + 256] = w_score[tid + 256];
    __syncthreads();

    const int w = tid >> 6, lane = tid & 63;
    for (int t = w; t < 64; t += 4) {
        const uint4 hv = *(const uint4*)(H_proj + ((size_t)b * 64 + t) * 512 + lane * 8);
        const int h0 = lane * 8;
        unsigned int ua[4] = {hv.x, hv.y, hv.z, hv.w};
        float acc = 0.f;
#pragma unroll
        for (int j = 0; j < 4; j++) {
            const float e0 = __uint_as_float(ua[j] << 16);
            const float e1 = __uint_as_float(ua[j] & 0xffff0000u);
            acc += tanh_fast(e0 + s_ph[h0 + 2 * j]) * s_w[h0 + 2 * j];
            acc += tanh_fast(e1 + s_ph[h0 + 2 * j + 1]) * s_w[h0 + 2 * j + 1];
        }
#pragma unroll
        for (int off = 32; off; off >>= 1) acc += __shfl_xor(acc, off);
        if (lane == 0) s_e[t] = acc;
    }
    __syncthreads();
    if (tid < 64) {
        float m = -1e30f;
        for (int t = 0; t < 64; ++t) m = fmaxf(m, s_e[t]);
        float sum = 0.f;
        for (int t = 0; t < 64; ++t) sum += __expf(s_e[t] - m);
        s_al[tid] = __expf(s_e[tid] - m) / sum;
    }
    __syncthreads();
    const unsigned int* bH = (const unsigned int*)(batch_H + (size_t)b * 64 * 512);
    float a0 = 0.f, a1 = 0.f;
    for (int t = 0; t < 64; ++t) {
        const unsigned int u = bH[t * 256 + tid];
        const float al = s_al[t];
        a0 = fmaf(al, __uint_as_float(u << 16), a0);
        a1 = fmaf(al, __uint_as_float(u & 0xffff0000u), a1);
    }
    const unsigned int o = ((unsigned int)f2bf(a1) << 16) | (unsigned int)f2bf(a0);
    ((unsigned int*)(ctx + (size_t)b * 512))[tid] = o;
}

// ---------------------------------------------------------------------------
extern "C" void kernel_launch(void* const* d_in, const int* in_sizes, int n_in,
                              void* d_out, int out_size, void* d_ws, size_t ws_size,
                              hipStream_t stream) {
    const float* batch_H = (const float*)d_in[0];   // [512,64,512]
    const int*   text    = (const int*)d_in[1];     // [512,26]
    const float* W_i2h   = (const float*)d_in[2];   // [512,512]
    const float* W_h2h   = (const float*)d_in[3];   // [512,512]
    const float* b_h2h   = (const float*)d_in[4];   // [512]
    const float* w_score = (const float*)d_in[5];   // [1,512]
    const float* W_ih    = (const float*)d_in[6];   // [2048,608]
    const float* b_ih    = (const float*)d_in[7];   // [2048]
    const float* W_hh    = (const float*)d_in[8];   // [2048,512]
    const float* b_hh    = (const float*)d_in[9];   // [2048]
    const float* W_gen   = (const float*)d_in[10];  // [96,512]
    const float* b_gen   = (const float*)d_in[11];  // [96]
    float* out = (float*)d_out;                     // [512,26,96]

    char* wsp = (char*)d_ws;
    auto alloc = [&](size_t bytes) { char* p = wsp; wsp += (bytes + 255) & ~(size_t)255; return p; };
    unsigned short* bH    = (unsigned short*)alloc(32768ull * 512 * 2);
    unsigned short* Hproj = (unsigned short*)alloc(32768ull * 512 * 2);
    unsigned short* hs    = (unsigned short*)alloc(512ull * NS * 512 * 2);
    unsigned short* hbuf0 = (unsigned short*)alloc(512ull * 512 * 2);
    unsigned short* hbuf1 = (unsigned short*)alloc(512ull * 512 * 2);
    unsigned short* ctx   = (unsigned short*)alloc(512ull * 512 * 2);
    unsigned short* Wi2hb = (unsigned short*)alloc(512ull * 512 * 2);
    unsigned short* Wh2hb = (unsigned short*)alloc(512ull * 512 * 2);
    unsigned short* Wgi   = (unsigned short*)alloc(2048ull * 512 * 2);
    unsigned short* Wgh   = (unsigned short*)alloc(2048ull * 512 * 2);
    unsigned short* Wgenb = (unsigned short*)alloc(96ull * 512 * 2);
    float* ph     = (float*)alloc(512ull * 512 * 4);
    float* cst    = (float*)alloc(512ull * 512 * 4);
    float* bsum_p = (float*)alloc(2048ull * 4);
    float* Wtok_p = (float*)alloc(96ull * 2048 * 4);
    unsigned short* hb[2] = {hbuf0, hbuf1};

    hipMemsetAsync(hbuf1, 0, 512ull * 512 * 2, stream);
    hipMemsetAsync(cst, 0, 512ull * 512 * 4, stream);

    conv_f32_bf16<<<16384, 256, 0, stream>>>(batch_H, bH, 4194304);
    conv_f32_bf16<<<256, 256, 0, stream>>>(W_i2h, Wi2hb, 65536);
    conv_f32_bf16<<<256, 256, 0, stream>>>(W_h2h, Wh2hb, 65536);
    conv_f32_bf16<<<48, 256, 0, stream>>>(W_gen, Wgenb, 12288);
    conv_w_perm<<<512, 256, 0, stream>>>(W_ih, 608, Wgi);
    conv_w_perm<<<512, 256, 0, stream>>>(W_hh, 512, Wgh);
    conv_wtok<<<768, 256, 0, stream>>>(W_ih, Wtok_p);
    bias_perm<<<8, 256, 0, stream>>>(b_ih, b_hh, bsum_p);

    // H_proj = batch_H @ W_i2h^T -> bf16 [32768,512], XCD-swizzled
    gemm_bf16<0, 1><<<dim3(512, 8), 256, 0, stream>>>(bH, 512, Wi2hb, 512, Hproj, 512, nullptr, 512, 0);

    for (int s = 0; s < NS; ++s) {
        const unsigned short* hprev = hb[(s + 1) & 1];
        // ph = hprev @ W_h2h^T + b_h2h (f32)
        gemm_bf16<3, 0><<<dim3(8, 8), 256, 0, stream>>>(hprev, 512, Wh2hb, 512, ph, 512, b_h2h, 512, 512);
        attn_kernel<<<512, 256, 0, stream>>>(Hproj, ph, w_score, bH, ctx);
        gates_lstm<<<dim3(32, 8), 256, 0, stream>>>(
            ctx, hprev, Wgi, Wgh, bsum_p, Wtok_p, text, s, cst, hs, hb[s & 1]);
    }

    // out = hs @ W_gen^T + b_gen (f32, N=96 masked in 128-wide tiles)
    gemm_bf16<3, 0><<<dim3(2, 208), 256, 0, stream>>>(hs, 512, Wgenb, 512, out, 96, b_gen, 512, 96);
}